// Round 1
// baseline (216.652 us; speedup 1.0000x reference)
//
#include <hip/hip_runtime.h>

#define NCLS 80
#define NO 85
#define NACH 3
#define NT 200
#define BSZ 8
#define CIN 256
#define ANCHOR_T 2.91f
#define EPSF 1e-9f

// cells per level (BS*NA*ny*nx) and flat level bases for obj/tobj buffers
#define S0 153600
#define S1_ 38400
#define S2_ 9600
#define LB0 0
#define LB1 153600
#define LB2 192000
#define TOTCELLS 201600

// ws layout (bytes): [tobj packed u64: 201600*8][accums: 32 floats][obj logits: 201600 f32]
#define WS_ACC_OFF  1612800
#define WS_OBJ_OFF  1612928
#define WS_ZERO_BYTES 1612928

// accum slots per level (l*8 + j): 0 lbox_sum, 1 n_valid, 2 S1, 3 S2, 4 T1, 5 T2, 6 fg ; slot 24 = done counter (u32)

// anchors: s/st == 4 for every level, so identical across levels
__device__ __constant__ float AW_[3] = {5.656854249f, 4.0f, 2.828427125f};
__device__ __constant__ float AH_[3] = {2.828427125f, 4.0f, 5.656854249f};

__device__ __forceinline__ float softplusf(float x) {
    return fmaxf(x, 0.0f) + log1pf(expf(-fabsf(x)));
}
__device__ __forceinline__ float sigmoidf_(float x) {
    return 1.0f / (1.0f + expf(-x));
}
__device__ __forceinline__ float wave_red(float v) {
    #pragma unroll
    for (int o = 32; o > 0; o >>= 1) v += __shfl_down(v, o);
    return v;
}

// Fused kernel:
//   blocks [0,525)        : objectness head (obj logits for all cells, all 3 anchors)
//   blocks [525,525+1125) : gathered-cell head + target assignment + CIoU + cls-BCE sums + tobj scatter
__global__ __launch_bounds__(256) void yolo_main(
    const float* __restrict__ f0, const float* __restrict__ w0, const float* __restrict__ b0,
    const float* __restrict__ f1, const float* __restrict__ w1, const float* __restrict__ b1,
    const float* __restrict__ f2, const float* __restrict__ w2, const float* __restrict__ b2,
    const float* __restrict__ targets,
    unsigned long long* __restrict__ tobj, float* __restrict__ acc, float* __restrict__ obj)
{
    const int bid = blockIdx.x;
    const int tid = threadIdx.x;

    __shared__ union __align__(16) {
        struct { float lw[3][CIN]; float part[8][32][13]; } h;  // 3072 + 13312 = 16384 B
        struct {
            float lf[8][260];      // staged feature vectors (stride 260: 16B-aligned rows)
            float pbox[8][4];      // box logits per entry
            float tbx[8][4];       // target boxes
            int   vb[8], eb[8], ec[8], egi[8], egj[8], ek[8];
            float r1[8], r2[8];    // per-entry lbox / count scratch
            float wsum[2][4];      // wave partials for S1/S2
        } g;
    } sm;

    if (bid < 525) {
        // ---------------- objectness head ----------------
        int l, blk0;
        if (bid < 400)      { l = 0; blk0 = 0; }
        else if (bid < 500) { l = 1; blk0 = 400; }
        else                { l = 2; blk0 = 500; }
        const int nx  = (l == 0) ? 80 : (l == 1) ? 40 : 20;
        const int ny  = nx;
        const int nxq = nx >> 2;
        const int perb = ny * nxq;                 // quads per image, also float4 channel stride
        const float* f  = (l == 0) ? f0 : (l == 1) ? f1 : f2;
        const float* w  = (l == 0) ? w0 : (l == 1) ? w1 : w2;
        const float* bi = (l == 0) ? b0 : (l == 1) ? b1 : b2;
        const int lob   = (l == 0) ? LB0 : (l == 1) ? LB1 : LB2;

        // stage the 3 objectness weight rows (a*85+4) into LDS
        for (int i = tid; i < 3 * CIN; i += 256) {
            int a = i >> 8, c = i & 255;
            sm.h.lw[a][c] = w[(a * NO + 4) * CIN + c];
        }
        __syncthreads();

        const int chunk = tid >> 5;        // 8 channel chunks of 32
        const int ql    = tid & 31;        // 32 position-quads per block
        const int q     = (bid - blk0) * 32 + ql;
        const int b  = q / perb;
        const int r  = q - b * perb;
        const int y  = r / nxq;
        const int xq = r - y * nxq;

        const float4* f4 = (const float4*)f;
        float a0[12];
        #pragma unroll
        for (int j = 0; j < 12; ++j) a0[j] = 0.f;
        const int c0 = chunk * 32;
        int base = ((b * CIN + c0) * ny + y) * nxq + xq;
        #pragma unroll 8
        for (int i = 0; i < 32; ++i) {
            float4 fv = f4[base + i * perb];
            #pragma unroll
            for (int a = 0; a < 3; ++a) {
                float wv = sm.h.lw[a][c0 + i];
                a0[a*4+0] += fv.x * wv;
                a0[a*4+1] += fv.y * wv;
                a0[a*4+2] += fv.z * wv;
                a0[a*4+3] += fv.w * wv;
            }
        }
        #pragma unroll
        for (int v = 0; v < 12; ++v) sm.h.part[chunk][ql][v] = a0[v];
        __syncthreads();
        for (int t = tid; t < 384; t += 256) {          // 32 quads x 12 (a,j) outputs
            int v = t >> 5, q2 = t & 31;
            float s = 0.f;
            #pragma unroll
            for (int ch = 0; ch < 8; ++ch) s += sm.h.part[ch][q2][v];
            int a = v >> 2, j = v & 3;
            int qq = (bid - blk0) * 32 + q2;
            int b2 = qq / perb; int r2 = qq - b2 * perb;
            int y2 = r2 / nxq;  int x2 = (r2 - y2 * nxq) * 4 + j;
            s += bi[a * NO + 4];
            obj[lob + ((b2 * 3 + a) * ny + y2) * nx + x2] = s;
        }
        return;
    }

    // ---------------- gathered entries ----------------
    // gid = (((l*5 + o)*25 + ntile)*3 + a); 8 entries (n = ntile*8..+7) per block
    int gid = bid - 525;
    const int a = gid % 3;  gid /= 3;
    const int ntile = gid % 25; gid /= 25;
    const int o = gid % 5;
    const int l = gid / 5;
    const int nx = (l == 0) ? 80 : (l == 1) ? 40 : 20;
    const int ny = nx;
    const float* f  = (l == 0) ? f0 : (l == 1) ? f1 : f2;
    const float* w  = (l == 0) ? w0 : (l == 1) ? w1 : w2;
    const float* bi = (l == 0) ? b0 : (l == 1) ? b1 : b2;
    const int ltb   = (l == 0) ? LB0 : (l == 1) ? LB1 : LB2;

    if (tid < 8) {
        const int e = tid;
        const int n = ntile * 8 + e;
        const float* tg = targets + n * 6;
        float tb = tg[0], tcl = tg[1];
        float gx = tg[2] * (float)nx, gy = tg[3] * (float)ny;
        float gw = tg[4] * (float)nx, gh = tg[5] * (float)ny;
        float rw = gw / AW_[a], rh = gh / AH_[a];
        float mr = fmaxf(fmaxf(rw, 1.f / rw), fmaxf(rh, 1.f / rh));
        bool ma = mr < ANCHOR_T;
        float ox = 0.f, oy = 0.f;
        bool s = true;
        if (o == 1)      { s = (fmodf(gx, 1.f) < 0.5f) && (gx > 1.f); ox = 0.5f; }
        else if (o == 2) { s = (fmodf(gy, 1.f) < 0.5f) && (gy > 1.f); oy = 0.5f; }
        else if (o == 3) { float gxi = (float)nx - gx; s = (fmodf(gxi, 1.f) < 0.5f) && (gxi > 1.f); ox = -0.5f; }
        else if (o == 4) { float gyi = (float)ny - gy; s = (fmodf(gyi, 1.f) < 0.5f) && (gyi > 1.f); oy = -0.5f; }
        int valid = (ma && s) ? 1 : 0;
        sm.g.vb[e] = valid;
        if (valid) {
            int gi = (int)(gx - ox);            // trunc == reference astype(int32); values > 0 here
            int gj = (int)(gy - oy);
            sm.g.tbx[e][0] = gx - (float)gi;    // tbox uses UNclipped gij
            sm.g.tbx[e][1] = gy - (float)gj;
            sm.g.tbx[e][2] = gw;
            sm.g.tbx[e][3] = gh;
            sm.g.egi[e] = min(max(gi, 0), nx - 1);
            sm.g.egj[e] = min(max(gj, 0), ny - 1);
            sm.g.eb[e]  = (int)tb;
            sm.g.ec[e]  = (int)tcl;
            sm.g.ek[e]  = o * 600 + a * 200 + n;   // scatter-order index (last wins)
        }
    }
    __syncthreads();

    bool any = false;
    #pragma unroll
    for (int e = 0; e < 8; ++e) any = any || (sm.g.vb[e] != 0);
    if (!any) return;

    // stage feature vectors of valid cells (one entry per step; lanes = channels)
    for (int e = 0; e < 8; ++e) {
        if (!sm.g.vb[e]) continue;
        sm.g.lf[e][tid] = f[((sm.g.eb[e] * CIN + tid) * ny + sm.g.egj[e]) * nx + sm.g.egi[e]];
    }
    __syncthreads();

    const int eg = tid >> 5;   // entry 0..7
    const int ol = tid & 31;   // output-channel lane
    float s1 = 0.f, s2 = 0.f;
    if (sm.g.vb[eg]) {
        const float4* lf4 = (const float4*)&sm.g.lf[eg][0];
        const int ecl = sm.g.ec[eg];
        #pragma unroll
        for (int ch = 0; ch < 3; ++ch) {
            int oc = ch * 32 + ol;               // 0..83 used: 0..3 box, 4..83 -> cls 0..79
            if (oc < 84) {
                int row = a * NO + oc + (oc >= 4 ? 1 : 0);   // skip obj channel 4
                const float4* wr4 = (const float4*)(w + row * CIN);
                float dacc = 0.f;
                #pragma unroll 8
                for (int c4 = 0; c4 < 64; ++c4) {
                    float4 wv = wr4[c4];
                    float4 fv = lf4[c4];
                    dacc += wv.x * fv.x + wv.y * fv.y + wv.z * fv.z + wv.w * fv.w;
                }
                dacc += bi[row];
                if (oc < 4) sm.g.pbox[eg][oc] = dacc;
                else {
                    if ((oc - 4) == ecl) s1 += softplusf(-dacc);
                    else                 s2 += softplusf(dacc);
                }
            }
        }
    }
    s1 = wave_red(s1);
    s2 = wave_red(s2);
    __syncthreads();                 // pbox complete; wsum scratch safe
    if ((tid & 63) == 0) { sm.g.wsum[0][tid >> 6] = s1; sm.g.wsum[1][tid >> 6] = s2; }
    __syncthreads();
    if (tid == 0) {
        float a1 = sm.g.wsum[0][0] + sm.g.wsum[0][1] + sm.g.wsum[0][2] + sm.g.wsum[0][3];
        float a2 = sm.g.wsum[1][0] + sm.g.wsum[1][1] + sm.g.wsum[1][2] + sm.g.wsum[1][3];
        atomicAdd(&acc[l * 8 + 2], a1);
        atomicAdd(&acc[l * 8 + 3], a2);
    }

    // per-entry CIoU + tobj scatter
    if (tid < 8) {
        if (sm.g.vb[tid]) {
            const int e = tid;
            float px = sigmoidf_(sm.g.pbox[e][0]) * 2.f - 0.5f;
            float py = sigmoidf_(sm.g.pbox[e][1]) * 2.f - 0.5f;
            float swp = sigmoidf_(sm.g.pbox[e][2]) * 2.f; float pw = swp * swp * AW_[a];
            float shp = sigmoidf_(sm.g.pbox[e][3]) * 2.f; float ph = shp * shp * AH_[a];
            float tx = sm.g.tbx[e][0], ty = sm.g.tbx[e][1], tw = sm.g.tbx[e][2], th = sm.g.tbx[e][3];
            float b1x1 = px - pw * 0.5f, b1x2 = px + pw * 0.5f;
            float b1y1 = py - ph * 0.5f, b1y2 = py + ph * 0.5f;
            float b2x1 = tx - tw * 0.5f, b2x2 = tx + tw * 0.5f;
            float b2y1 = ty - th * 0.5f, b2y2 = ty + th * 0.5f;
            float iw = fmaxf(fminf(b1x2, b2x2) - fmaxf(b1x1, b2x1), 0.f);
            float ih = fmaxf(fminf(b1y2, b2y2) - fmaxf(b1y1, b2y1), 0.f);
            float inter = iw * ih;
            float uni = pw * ph + tw * th - inter + EPSF;
            float iou = inter / uni;
            float cw = fmaxf(b1x2, b2x2) - fminf(b1x1, b2x1);
            float chh = fmaxf(b1y2, b2y2) - fminf(b1y1, b2y1);
            float c2 = cw * cw + chh * chh + EPSF;
            float dx = b2x1 + b2x2 - b1x1 - b1x2;
            float dy = b2y1 + b2y2 - b1y1 - b1y2;
            float rho2 = (dx * dx + dy * dy) * 0.25f;
            float dat = atanf(tw / (th + EPSF)) - atanf(pw / (ph + EPSF));
            float v = 0.4052847346f * dat * dat;       // 4/pi^2
            float alpha = v / (v - iou + (1.f + EPSF));
            float ciou = iou - (rho2 / c2 + v * alpha);
            int idx = ltb + ((sm.g.eb[e] * 3 + a) * ny + sm.g.egj[e]) * nx + sm.g.egi[e];
            unsigned long long pk =
                ((unsigned long long)(unsigned)(sm.g.ek[e] + 1) << 32) |
                (unsigned long long)__float_as_uint(fmaxf(ciou, 0.f));
            atomicMax(&tobj[idx], pk);                 // high bits = scatter order -> last write wins
            sm.g.r1[tid] = 1.f - ciou;
            sm.g.r2[tid] = 1.f;
        } else {
            sm.g.r1[tid] = 0.f;
            sm.g.r2[tid] = 0.f;
        }
    }
    __syncthreads();
    if (tid == 0) {
        float lb = 0.f, nv = 0.f;
        #pragma unroll
        for (int e = 0; e < 8; ++e) { lb += sm.g.r1[e]; nv += sm.g.r2[e]; }
        if (nv > 0.f) {
            atomicAdd(&acc[l * 8 + 0], lb);
            atomicAdd(&acc[l * 8 + 1], nv);
        }
    }
}

// objectness BCE sums + grid-wide finalize (last block writes the 3 outputs)
#define NBLK_OBJ 788
__global__ __launch_bounds__(256) void yolo_obj(
    const float* __restrict__ obj, const unsigned long long* __restrict__ tobj,
    float* __restrict__ acc, float* __restrict__ out)
{
    const int bid = blockIdx.x, tid = threadIdx.x;
    int l, start, cnt, lb;
    if (bid < 600)      { l = 0; start = bid * 256;         cnt = S0;  lb = LB0; }
    else if (bid < 750) { l = 1; start = (bid - 600) * 256; cnt = S1_; lb = LB1; }
    else                { l = 2; start = (bid - 750) * 256; cnt = S2_; lb = LB2; }
    int idx = start + tid;
    float t1 = 0.f, t2 = 0.f, fg = 0.f;
    if (idx < cnt) {
        float x = obj[lb + idx];
        unsigned long long p = tobj[lb + idx];
        float t = (p != 0ull) ? __uint_as_float((unsigned)(p & 0xffffffffull)) : 0.f;
        t1 = t * softplusf(-x);
        t2 = (1.f - t) * softplusf(x);
        fg = (t > 0.f) ? 1.f : 0.f;
    }
    t1 = wave_red(t1); t2 = wave_red(t2); fg = wave_red(fg);
    __shared__ float wr_[3][4];
    __shared__ int lastFlag;
    if ((tid & 63) == 0) { int w = tid >> 6; wr_[0][w] = t1; wr_[1][w] = t2; wr_[2][w] = fg; }
    __syncthreads();
    if (tid == 0) {
        atomicAdd(&acc[l * 8 + 4], wr_[0][0] + wr_[0][1] + wr_[0][2] + wr_[0][3]);
        atomicAdd(&acc[l * 8 + 5], wr_[1][0] + wr_[1][1] + wr_[1][2] + wr_[1][3]);
        atomicAdd(&acc[l * 8 + 6], wr_[2][0] + wr_[2][1] + wr_[2][2] + wr_[2][3]);
        __threadfence();
        unsigned old = atomicAdd((unsigned*)&acc[24], 1u);
        lastFlag = (old == NBLK_OBJ - 1) ? 1 : 0;
    }
    __syncthreads();
    if (lastFlag && tid == 0) {
        const float bal[3]   = {4.f, 1.f, 0.25f};
        const float numel[3] = {(float)S0, (float)S1_, (float)S2_};
        float lbox = 0.f, lobj = 0.f, lcls = 0.f;
        for (int i = 0; i < 3; ++i) {
            float lbs = atomicAdd(&acc[i * 8 + 0], 0.f);   // coherent (agent-scope RMW) reads
            float nv  = atomicAdd(&acc[i * 8 + 1], 0.f);
            float s1  = atomicAdd(&acc[i * 8 + 2], 0.f);
            float s2  = atomicAdd(&acc[i * 8 + 3], 0.f);
            float T1  = atomicAdd(&acc[i * 8 + 4], 0.f);
            float T2  = atomicAdd(&acc[i * 8 + 5], 0.f);
            float fgc = atomicAdd(&acc[i * 8 + 6], 0.f);
            lbox += lbs / fmaxf(nv, 1.f);
            float pwc = nv * (float)(NCLS - 1) * 0.5f / fmaxf(nv, 2.f);
            lcls += (pwc * s1 + s2) / fmaxf(nv * (float)NCLS, 1.f);
            float bg = numel[i] - fgc;
            float pwo = bg * 0.5f / fmaxf(fgc, 2.f);
            lobj += (pwo * T1 + T2) / numel[i] * bal[i];
        }
        out[0] = lbox * 0.05f;
        out[1] = lobj * 1.0f;
        out[2] = lcls * 0.5f;
    }
}

extern "C" void kernel_launch(void* const* d_in, const int* in_sizes, int n_in,
                              void* d_out, int out_size, void* d_ws, size_t ws_size,
                              hipStream_t stream) {
    (void)in_sizes; (void)n_in; (void)out_size; (void)ws_size;
    // setup_inputs dict order: feat0,w0,b0, feat1,w1,b1, feat2,w2,b2, targets
    const float* f0 = (const float*)d_in[0];
    const float* w0 = (const float*)d_in[1];
    const float* b0 = (const float*)d_in[2];
    const float* f1 = (const float*)d_in[3];
    const float* w1 = (const float*)d_in[4];
    const float* b1 = (const float*)d_in[5];
    const float* f2 = (const float*)d_in[6];
    const float* w2 = (const float*)d_in[7];
    const float* b2 = (const float*)d_in[8];
    const float* tg = (const float*)d_in[9];
    float* out = (float*)d_out;

    char* ws = (char*)d_ws;
    unsigned long long* tobj = (unsigned long long*)ws;
    float* acc = (float*)(ws + WS_ACC_OFF);
    float* obj = (float*)(ws + WS_OBJ_OFF);

    hipMemsetAsync(d_ws, 0, WS_ZERO_BYTES, stream);
    yolo_main<<<dim3(525 + 1125), dim3(256), 0, stream>>>(f0, w0, b0, f1, w1, b1, f2, w2, b2, tg, tobj, acc, obj);
    yolo_obj<<<dim3(NBLK_OBJ), dim3(256), 0, stream>>>(obj, tobj, acc, out);
}

// Round 2
// 203.620 us; speedup vs baseline: 1.0640x; 1.0640x over previous
//
#include <hip/hip_runtime.h>

#define NCLS 80
#define NO 85
#define NT 200
#define BSZ 8
#define CIN 256
#define ANCHOR_T 2.91f
#define EPSF 1e-9f

// cells per level (BS*NA*ny*nx) and flat level bases for obj/tobj buffers
#define S0 153600
#define S1_ 38400
#define S2_ 9600
#define LB0 0
#define LB1 153600
#define LB2 192000

// ws layout (bytes):
//   [tobj packed u64 : 201600*8 = 1612800]
//   [accums          : 32 floats = 128]      (zeroed with tobj)
//   [obj logits      : 201600*4 = 806400]    (fully overwritten, no zeroing)
//   [scatter list    : 3072 ints]
#define WS_ACC_OFF   1612800
#define WS_OBJ_OFF   1612928
#define WS_LIST_OFF  2419328
#define WS_ZERO_BYTES 1612928

// accum slots (l*8+j): 0 lbox_sum, 1 n_valid, 2 S1(cls target), 3 S2(cls other),
//                      5 T2_base (sum softplus(obj logit) over all cells)
// acc[25] (as uint): scatter-list count

__device__ __constant__ float AW_[3] = {5.656854249f, 4.0f, 2.828427125f};
__device__ __constant__ float AH_[3] = {2.828427125f, 4.0f, 5.656854249f};

__device__ __forceinline__ float softplusf(float x) {
    return fmaxf(x, 0.0f) + log1pf(expf(-fabsf(x)));
}
__device__ __forceinline__ float sigmoidf_(float x) {
    return 1.0f / (1.0f + expf(-x));
}
__device__ __forceinline__ float wave_red(float v) {
    #pragma unroll
    for (int o = 32; o > 0; o >>= 1) v += __shfl_down(v, o);
    return v;
}

#define NHEAD 1050   // L0: 800 blocks, L1: 200, L2: 50 (16 quads/block)
#define NGATH 1125

__global__ __launch_bounds__(256) void yolo_main(
    const float* __restrict__ f0, const float* __restrict__ w0, const float* __restrict__ b0,
    const float* __restrict__ f1, const float* __restrict__ w1, const float* __restrict__ b1,
    const float* __restrict__ f2, const float* __restrict__ w2, const float* __restrict__ b2,
    const float* __restrict__ targets,
    unsigned long long* __restrict__ tobj, float* __restrict__ acc, float* __restrict__ obj,
    int* __restrict__ list)
{
    const int bid = blockIdx.x;
    const int tid = threadIdx.x;

    __shared__ union __align__(16) {
        struct { float lw[3][CIN]; float part[16][16][13]; float ws_[4]; } h;  // 3072+13312+16
        struct {
            float lf[8][260];
            float pbox[8][4];
            float tbx[8][4];
            int   vb[8], eb[8], ec[8], egi[8], egj[8], ek[8];
            float r1[8], r2[8];
            float wsum[2][4];
        } g;
    } sm;

    if (bid < NHEAD) {
        // ---------------- objectness head (+ t=0 BCE base sum) ----------------
        int l, blk0;
        if (bid < 800)       { l = 0; blk0 = 0; }
        else if (bid < 1000) { l = 1; blk0 = 800; }
        else                 { l = 2; blk0 = 1000; }
        const int nx  = (l == 0) ? 80 : (l == 1) ? 40 : 20;
        const int ny  = nx;
        const int nxq = nx >> 2;
        const int perb = ny * nxq;                 // float4 channel stride
        const float* f  = (l == 0) ? f0 : (l == 1) ? f1 : f2;
        const float* w  = (l == 0) ? w0 : (l == 1) ? w1 : w2;
        const float* bi = (l == 0) ? b0 : (l == 1) ? b1 : b2;
        const int lob   = (l == 0) ? LB0 : (l == 1) ? LB1 : LB2;

        for (int i = tid; i < 3 * CIN; i += 256) {
            int a = i >> 8, c = i & 255;
            sm.h.lw[a][c] = w[(a * NO + 4) * CIN + c];
        }
        __syncthreads();

        const int chunk = tid >> 4;        // 16 channel chunks of 16
        const int ql    = tid & 15;        // 16 position-quads per block
        const int q     = (bid - blk0) * 16 + ql;
        const int b  = q / perb;
        const int r  = q - b * perb;
        const int y  = r / nxq;
        const int xq = r - y * nxq;

        const float4* f4 = (const float4*)f;
        const int c0 = chunk * 16;
        const int base = ((b * CIN + c0) * ny + y) * nxq + xq;

        float4 buf[16];
        #pragma unroll
        for (int i = 0; i < 16; ++i) buf[i] = f4[base + i * perb];   // 16 loads in flight

        float a0[12];
        #pragma unroll
        for (int j = 0; j < 12; ++j) a0[j] = 0.f;
        #pragma unroll
        for (int i = 0; i < 16; ++i) {
            float4 fv = buf[i];
            #pragma unroll
            for (int a = 0; a < 3; ++a) {
                float wv = sm.h.lw[a][c0 + i];
                a0[a*4+0] += fv.x * wv;
                a0[a*4+1] += fv.y * wv;
                a0[a*4+2] += fv.z * wv;
                a0[a*4+3] += fv.w * wv;
            }
        }
        #pragma unroll
        for (int v = 0; v < 12; ++v) sm.h.part[chunk][ql][v] = a0[v];
        __syncthreads();

        float sp = 0.f;
        if (tid < 192) {                       // 16 quads x 12 (a,j) outputs
            int q2 = tid / 12, v = tid - q2 * 12;
            float s = 0.f;
            #pragma unroll
            for (int ch = 0; ch < 16; ++ch) s += sm.h.part[ch][q2][v];
            int a = v >> 2, j = v & 3;
            int qq = (bid - blk0) * 16 + q2;
            int b2 = qq / perb; int r2 = qq - b2 * perb;
            int y2 = r2 / nxq;  int x2 = (r2 - y2 * nxq) * 4 + j;
            s += bi[a * NO + 4];
            obj[lob + ((b2 * 3 + a) * ny + y2) * nx + x2] = s;
            sp = softplusf(s);                 // t=0 objectness BCE term
        }
        sp = wave_red(sp);
        if ((tid & 63) == 0) sm.h.ws_[tid >> 6] = sp;
        __syncthreads();
        if (tid == 0)
            atomicAdd(&acc[l * 8 + 5], sm.h.ws_[0] + sm.h.ws_[1] + sm.h.ws_[2] + sm.h.ws_[3]);
        return;
    }

    // ---------------- gathered entries ----------------
    int gid = bid - NHEAD;
    const int a = gid % 3;  gid /= 3;
    const int ntile = gid % 25; gid /= 25;
    const int o = gid % 5;
    const int l = gid / 5;
    const int nx = (l == 0) ? 80 : (l == 1) ? 40 : 20;
    const int ny = nx;
    const float* f  = (l == 0) ? f0 : (l == 1) ? f1 : f2;
    const float* w  = (l == 0) ? w0 : (l == 1) ? w1 : w2;
    const float* bi = (l == 0) ? b0 : (l == 1) ? b1 : b2;
    const int ltb   = (l == 0) ? LB0 : (l == 1) ? LB1 : LB2;

    if (tid < 8) {
        const int e = tid;
        const int n = ntile * 8 + e;
        const float* tg = targets + n * 6;
        float tb = tg[0], tcl = tg[1];
        float gx = tg[2] * (float)nx, gy = tg[3] * (float)ny;
        float gw = tg[4] * (float)nx, gh = tg[5] * (float)ny;
        float rw = gw / AW_[a], rh = gh / AH_[a];
        float mr = fmaxf(fmaxf(rw, 1.f / rw), fmaxf(rh, 1.f / rh));
        bool ma = mr < ANCHOR_T;
        float ox = 0.f, oy = 0.f;
        bool s = true;
        if (o == 1)      { s = (fmodf(gx, 1.f) < 0.5f) && (gx > 1.f); ox = 0.5f; }
        else if (o == 2) { s = (fmodf(gy, 1.f) < 0.5f) && (gy > 1.f); oy = 0.5f; }
        else if (o == 3) { float gxi = (float)nx - gx; s = (fmodf(gxi, 1.f) < 0.5f) && (gxi > 1.f); ox = -0.5f; }
        else if (o == 4) { float gyi = (float)ny - gy; s = (fmodf(gyi, 1.f) < 0.5f) && (gyi > 1.f); oy = -0.5f; }
        int valid = (ma && s) ? 1 : 0;
        sm.g.vb[e] = valid;
        if (valid) {
            int gi = (int)(gx - ox);
            int gj = (int)(gy - oy);
            sm.g.tbx[e][0] = gx - (float)gi;
            sm.g.tbx[e][1] = gy - (float)gj;
            sm.g.tbx[e][2] = gw;
            sm.g.tbx[e][3] = gh;
            sm.g.egi[e] = min(max(gi, 0), nx - 1);
            sm.g.egj[e] = min(max(gj, 0), ny - 1);
            sm.g.eb[e]  = (int)tb;
            sm.g.ec[e]  = (int)tcl;
            sm.g.ek[e]  = o * 600 + a * 200 + n;   // scatter-order index (last wins)
        }
    }
    __syncthreads();

    bool any = false;
    #pragma unroll
    for (int e = 0; e < 8; ++e) any = any || (sm.g.vb[e] != 0);
    if (!any) return;

    for (int e = 0; e < 8; ++e) {
        if (!sm.g.vb[e]) continue;
        sm.g.lf[e][tid] = f[((sm.g.eb[e] * CIN + tid) * ny + sm.g.egj[e]) * nx + sm.g.egi[e]];
    }
    __syncthreads();

    const int eg = tid >> 5;
    const int ol = tid & 31;
    float s1 = 0.f, s2 = 0.f;
    if (sm.g.vb[eg]) {
        const float4* lf4 = (const float4*)&sm.g.lf[eg][0];
        const int ecl = sm.g.ec[eg];
        #pragma unroll
        for (int ch = 0; ch < 3; ++ch) {
            int oc = ch * 32 + ol;
            if (oc < 84) {
                int row = a * NO + oc + (oc >= 4 ? 1 : 0);
                const float4* wr4 = (const float4*)(w + row * CIN);
                float dacc = 0.f;
                #pragma unroll 8
                for (int c4 = 0; c4 < 64; ++c4) {
                    float4 wv = wr4[c4];
                    float4 fv = lf4[c4];
                    dacc += wv.x * fv.x + wv.y * fv.y + wv.z * fv.z + wv.w * fv.w;
                }
                dacc += bi[row];
                if (oc < 4) sm.g.pbox[eg][oc] = dacc;
                else {
                    if ((oc - 4) == ecl) s1 += softplusf(-dacc);
                    else                 s2 += softplusf(dacc);
                }
            }
        }
    }
    s1 = wave_red(s1);
    s2 = wave_red(s2);
    __syncthreads();
    if ((tid & 63) == 0) { sm.g.wsum[0][tid >> 6] = s1; sm.g.wsum[1][tid >> 6] = s2; }
    __syncthreads();
    if (tid == 0) {
        float a1 = sm.g.wsum[0][0] + sm.g.wsum[0][1] + sm.g.wsum[0][2] + sm.g.wsum[0][3];
        float a2 = sm.g.wsum[1][0] + sm.g.wsum[1][1] + sm.g.wsum[1][2] + sm.g.wsum[1][3];
        atomicAdd(&acc[l * 8 + 2], a1);
        atomicAdd(&acc[l * 8 + 3], a2);
    }

    if (tid < 8) {
        if (sm.g.vb[tid]) {
            const int e = tid;
            float px = sigmoidf_(sm.g.pbox[e][0]) * 2.f - 0.5f;
            float py = sigmoidf_(sm.g.pbox[e][1]) * 2.f - 0.5f;
            float swp = sigmoidf_(sm.g.pbox[e][2]) * 2.f; float pw = swp * swp * AW_[a];
            float shp = sigmoidf_(sm.g.pbox[e][3]) * 2.f; float ph = shp * shp * AH_[a];
            float tx = sm.g.tbx[e][0], ty = sm.g.tbx[e][1], tw = sm.g.tbx[e][2], th = sm.g.tbx[e][3];
            float b1x1 = px - pw * 0.5f, b1x2 = px + pw * 0.5f;
            float b1y1 = py - ph * 0.5f, b1y2 = py + ph * 0.5f;
            float b2x1 = tx - tw * 0.5f, b2x2 = tx + tw * 0.5f;
            float b2y1 = ty - th * 0.5f, b2y2 = ty + th * 0.5f;
            float iw = fmaxf(fminf(b1x2, b2x2) - fmaxf(b1x1, b2x1), 0.f);
            float ih = fmaxf(fminf(b1y2, b2y2) - fmaxf(b1y1, b2y1), 0.f);
            float inter = iw * ih;
            float uni = pw * ph + tw * th - inter + EPSF;
            float iou = inter / uni;
            float cw = fmaxf(b1x2, b2x2) - fminf(b1x1, b2x1);
            float chh = fmaxf(b1y2, b2y2) - fminf(b1y1, b2y1);
            float c2 = cw * cw + chh * chh + EPSF;
            float dx = b2x1 + b2x2 - b1x1 - b1x2;
            float dy = b2y1 + b2y2 - b1y1 - b1y2;
            float rho2 = (dx * dx + dy * dy) * 0.25f;
            float dat = atanf(tw / (th + EPSF)) - atanf(pw / (ph + EPSF));
            float v = 0.4052847346f * dat * dat;
            float alpha = v / (v - iou + (1.f + EPSF));
            float ciou = iou - (rho2 / c2 + v * alpha);
            int idx = ltb + ((sm.g.eb[e] * 3 + a) * ny + sm.g.egj[e]) * nx + sm.g.egi[e];
            unsigned long long pk =
                ((unsigned long long)(unsigned)(sm.g.ek[e] + 1) << 32) |
                (unsigned long long)__float_as_uint(fmaxf(ciou, 0.f));
            atomicMax(&tobj[idx], pk);
            unsigned p = atomicAdd((unsigned*)&acc[25], 1u);
            list[p] = idx;
            sm.g.r1[tid] = 1.f - ciou;
            sm.g.r2[tid] = 1.f;
        } else {
            sm.g.r1[tid] = 0.f;
            sm.g.r2[tid] = 0.f;
        }
    }
    __syncthreads();
    if (tid == 0) {
        float lb = 0.f, nv = 0.f;
        #pragma unroll
        for (int e = 0; e < 8; ++e) { lb += sm.g.r1[e]; nv += sm.g.r2[e]; }
        if (nv > 0.f) {
            atomicAdd(&acc[l * 8 + 0], lb);
            atomicAdd(&acc[l * 8 + 1], nv);
        }
    }
}

// single-block finalize: correct scattered cells' objectness BCE, compute outputs
__global__ __launch_bounds__(1024) void yolo_fin(
    const float* __restrict__ obj, unsigned long long* __restrict__ tobj,
    const float* __restrict__ acc, const int* __restrict__ list,
    float* __restrict__ out)
{
    const int tid = threadIdx.x;
    __shared__ float corr[3][3];   // [level][0]=T1, [1]=sum t*sp(x), [2]=fg
    if (tid < 9) ((float*)corr)[tid] = 0.f;
    __syncthreads();

    const unsigned n = ((const unsigned*)acc)[25];
    for (unsigned i = tid; i < n; i += 1024) {
        int idx = list[i];
        unsigned long long old = atomicExch(&tobj[idx], 0ull);   // dedupe: first taker wins
        if (old != 0ull) {
            float t = __uint_as_float((unsigned)(old & 0xffffffffull));
            float x = obj[idx];
            int l = (idx >= LB2) ? 2 : (idx >= LB1) ? 1 : 0;
            atomicAdd(&corr[l][0], t * softplusf(-x));
            atomicAdd(&corr[l][1], t * softplusf(x));
            atomicAdd(&corr[l][2], (t > 0.f) ? 1.f : 0.f);
        }
    }
    __syncthreads();
    if (tid == 0) {
        const float bal[3]   = {4.f, 1.f, 0.25f};
        const float numel[3] = {(float)S0, (float)S1_, (float)S2_};
        float lbox = 0.f, lobj = 0.f, lcls = 0.f;
        for (int i = 0; i < 3; ++i) {
            float lbs = acc[i * 8 + 0];
            float nv  = acc[i * 8 + 1];
            float s1  = acc[i * 8 + 2];
            float s2  = acc[i * 8 + 3];
            float T2b = acc[i * 8 + 5];
            float T1  = corr[i][0];
            float T2  = T2b - corr[i][1];
            float fg  = corr[i][2];
            lbox += lbs / fmaxf(nv, 1.f);
            float pwc = nv * (float)(NCLS - 1) * 0.5f / fmaxf(nv, 2.f);
            lcls += (pwc * s1 + s2) / fmaxf(nv * (float)NCLS, 1.f);
            float bg = numel[i] - fg;
            float pwo = bg * 0.5f / fmaxf(fg, 2.f);
            lobj += (pwo * T1 + T2) / numel[i] * bal[i];
        }
        out[0] = lbox * 0.05f;
        out[1] = lobj * 1.0f;
        out[2] = lcls * 0.5f;
    }
}

extern "C" void kernel_launch(void* const* d_in, const int* in_sizes, int n_in,
                              void* d_out, int out_size, void* d_ws, size_t ws_size,
                              hipStream_t stream) {
    (void)in_sizes; (void)n_in; (void)out_size; (void)ws_size;
    const float* f0 = (const float*)d_in[0];
    const float* w0 = (const float*)d_in[1];
    const float* b0 = (const float*)d_in[2];
    const float* f1 = (const float*)d_in[3];
    const float* w1 = (const float*)d_in[4];
    const float* b1 = (const float*)d_in[5];
    const float* f2 = (const float*)d_in[6];
    const float* w2 = (const float*)d_in[7];
    const float* b2 = (const float*)d_in[8];
    const float* tg = (const float*)d_in[9];
    float* out = (float*)d_out;

    char* ws = (char*)d_ws;
    unsigned long long* tobj = (unsigned long long*)ws;
    float* acc = (float*)(ws + WS_ACC_OFF);
    float* obj = (float*)(ws + WS_OBJ_OFF);
    int* list  = (int*)(ws + WS_LIST_OFF);

    hipMemsetAsync(d_ws, 0, WS_ZERO_BYTES, stream);
    yolo_main<<<dim3(NHEAD + NGATH), dim3(256), 0, stream>>>(f0, w0, b0, f1, w1, b1, f2, w2, b2, tg, tobj, acc, obj, list);
    yolo_fin<<<dim3(1), dim3(1024), 0, stream>>>(obj, tobj, acc, list, out);
}